// Round 2
// baseline (585.246 us; speedup 1.0000x reference)
//
#include <hip/hip_runtime.h>

// Problem constants (match reference file)
constexpr int D = 128;       // node feature dim
constexpr int R = 64;        // edge feature dim (in = out)
constexpr int CAP = 64;      // per-dst bucket capacity (in-deg ~ Poisson(16))
constexpr int OVF_CAP = 65536;

static __device__ __forceinline__ float4 f4fma(float a, float4 w, float4 c) {
  c.x = fmaf(a, w.x, c.x); c.y = fmaf(a, w.y, c.y);
  c.z = fmaf(a, w.z, c.z); c.w = fmaf(a, w.w, c.w);
  return c;
}

__global__ void k_init(int* deg_out, int* deg_in, int* cursor, int* ovf_cnt, int n) {
  int i = blockIdx.x * blockDim.x + threadIdx.x;
  if (i < n) { deg_out[i] = 1; deg_in[i] = 1; cursor[i] = 0; }  // =1: self loop
  if (i == 0) ovf_cnt[0] = 0;
}

__global__ void k_deg(const int* __restrict__ src, const int* __restrict__ dst,
                      int* deg_out, int* deg_in, int e) {
  int i = blockIdx.x * blockDim.x + threadIdx.x;
  if (i < e) {
    atomicAdd(&deg_out[src[i]], 1);
    atomicAdd(&deg_in[dst[i]], 1);
  }
}

__global__ void k_norm(const int* __restrict__ deg_out, const int* __restrict__ deg_in,
                       float* ns, float* nd, int n) {
  int i = blockIdx.x * blockDim.x + threadIdx.x;
  if (i < n) {
    ns[i] = rsqrtf((float)deg_out[i]);
    nd[i] = rsqrtf((float)deg_in[i]);
  }
}

__global__ void k_fill(const int* __restrict__ src, const int* __restrict__ dst,
                       int* cursor, int* bucket, int* ovf_cnt, int2* ovf, int e) {
  int i = blockIdx.x * blockDim.x + threadIdx.x;
  if (i >= e) return;
  int d = dst[i], s = src[i];
  int slot = atomicAdd(&cursor[d], 1);
  if (slot < CAP) bucket[(size_t)d * CAP + slot] = s;
  else {
    int oi = atomicAdd(ovf_cnt, 1);
    if (oi < OVF_CAP) ovf[oi] = make_int2(s, d);
  }
}

// One 32-lane group per node; each lane holds a float4 (D=128 = 32*4).
// agg[v] = x[v]*ns[v] (self loop) + sum_{(s->v)} x[s]*ns[s]   (norm_dst applied later)
__global__ __launch_bounds__(256) void k_agg(const float* __restrict__ X,
                                             const float* __restrict__ ns,
                                             const int* __restrict__ cursor,
                                             const int* __restrict__ bucket,
                                             float* __restrict__ agg, int n) {
  int g = threadIdx.x >> 5, lane = threadIdx.x & 31;
  int v = blockIdx.x * 8 + g;
  if (v >= n) return;
  float4 acc;
  {
    float4 xv = ((const float4*)(X + (size_t)v * D))[lane];
    float s = ns[v];
    acc.x = xv.x * s; acc.y = xv.y * s; acc.z = xv.z * s; acc.w = xv.w * s;
  }
  int cnt = min(cursor[v], CAP);
  const int* bk = bucket + (size_t)v * CAP;
  int i = 0;
  for (; i + 4 <= cnt; i += 4) {
    int s0 = bk[i], s1 = bk[i + 1], s2 = bk[i + 2], s3 = bk[i + 3];
    float n0 = ns[s0], n1 = ns[s1], n2 = ns[s2], n3 = ns[s3];
    float4 x0 = ((const float4*)(X + (size_t)s0 * D))[lane];
    float4 x1 = ((const float4*)(X + (size_t)s1 * D))[lane];
    float4 x2 = ((const float4*)(X + (size_t)s2 * D))[lane];
    float4 x3 = ((const float4*)(X + (size_t)s3 * D))[lane];
    acc = f4fma(n0, x0, acc); acc = f4fma(n1, x1, acc);
    acc = f4fma(n2, x2, acc); acc = f4fma(n3, x3, acc);
  }
  for (; i < cnt; ++i) {
    int s0 = bk[i];
    float4 x0 = ((const float4*)(X + (size_t)s0 * D))[lane];
    acc = f4fma(ns[s0], x0, acc);
  }
  ((float4*)(agg + (size_t)v * D))[lane] = acc;
}

// Rare overflow edges (slot >= CAP): f32 atomics, normally zero work.
__global__ __launch_bounds__(128) void k_ovf(const float* __restrict__ X,
                                             const float* __restrict__ ns,
                                             const int* __restrict__ ovf_cnt,
                                             const int2* __restrict__ ovf,
                                             float* agg) {
  int m = min(ovf_cnt[0], OVF_CAP);
  int t = threadIdx.x;
  for (int i = blockIdx.x; i < m; i += gridDim.x) {
    int2 e = ovf[i];
    atomicAdd(&agg[(size_t)e.y * D + t], X[(size_t)e.x * D + t] * ns[e.x]);
  }
}

// out[r] = relu( (agg[r] * nd[r]) @ W + b ) ; nd folded into epilogue.
// 256 thr: thread handles 2 rows x 4 cols; 16 rows per block-iter; W in LDS (64KB).
__global__ __launch_bounds__(256) void k_gemm_relu(const float* __restrict__ A,
                                                   const float* __restrict__ ndv,
                                                   const float* __restrict__ W,
                                                   const float* __restrict__ bias,
                                                   float* __restrict__ out, int n) {
  __shared__ float Wl[D * D];  // 64 KiB
  int t = threadIdx.x;
  for (int i = t; i < (D * D) / 4; i += 256) ((float4*)Wl)[i] = ((const float4*)W)[i];
  __syncthreads();
  int r2 = (t >> 5) * 2;       // 0,2,...,14
  int cg = (t & 31) * 4;       // col group
  float4 bb = *(const float4*)(bias + cg);
  for (int row0 = blockIdx.x * 16; row0 < n; row0 += gridDim.x * 16) {
    int ra = row0 + r2, rb = ra + 1;
    if (ra >= n) continue;     // no __syncthreads inside loop -> safe
    bool hb = (rb < n);
    const float4* A0 = (const float4*)(A + (size_t)ra * D);
    const float4* A1 = (const float4*)(A + (size_t)(hb ? rb : ra) * D);
    float4 s0 = make_float4(0.f, 0.f, 0.f, 0.f);
    float4 s1 = make_float4(0.f, 0.f, 0.f, 0.f);
#pragma unroll 8
    for (int k4 = 0; k4 < 32; ++k4) {
      float4 a0 = A0[k4];
      float4 a1 = A1[k4];
      const float* wp = Wl + (k4 << 9) + cg;
      float4 w;
      w = *(const float4*)(wp);       s0 = f4fma(a0.x, w, s0); s1 = f4fma(a1.x, w, s1);
      w = *(const float4*)(wp + 128); s0 = f4fma(a0.y, w, s0); s1 = f4fma(a1.y, w, s1);
      w = *(const float4*)(wp + 256); s0 = f4fma(a0.z, w, s0); s1 = f4fma(a1.z, w, s1);
      w = *(const float4*)(wp + 384); s0 = f4fma(a0.w, w, s0); s1 = f4fma(a1.w, w, s1);
    }
    {
      float ndr = ndv[ra];
      float4 o;
      o.x = fmaxf(fmaf(s0.x, ndr, bb.x), 0.f);
      o.y = fmaxf(fmaf(s0.y, ndr, bb.y), 0.f);
      o.z = fmaxf(fmaf(s0.z, ndr, bb.z), 0.f);
      o.w = fmaxf(fmaf(s0.w, ndr, bb.w), 0.f);
      *(float4*)(out + (size_t)ra * D + cg) = o;
    }
    if (hb) {
      float ndr = ndv[rb];
      float4 o;
      o.x = fmaxf(fmaf(s1.x, ndr, bb.x), 0.f);
      o.y = fmaxf(fmaf(s1.y, ndr, bb.y), 0.f);
      o.z = fmaxf(fmaf(s1.z, ndr, bb.z), 0.f);
      o.w = fmaxf(fmaf(s1.w, ndr, bb.w), 0.f);
      *(float4*)(out + (size_t)rb * D + cg) = o;
    }
  }
}

// e_h rows [0,E): text_h[row] @ relW + relb ; rows [E,E+N): relb (zero text).
// Register-blocked: each thread computes 4 rows x 16 cols. 4 col-threads per
// row-group share W LDS reads via same-address broadcast on the A side.
// W-LDS traffic per row: 4 KB (was 16 KB) -> ~3.5 GB total ~ 50 us.
__global__ __launch_bounds__(256) void k_rel(const float* __restrict__ T,
                                             const float* __restrict__ Wr,
                                             const float* __restrict__ br,
                                             float* __restrict__ out,
                                             int e, int ntot) {
  __shared__ float Wl[R * R];  // 16 KiB
  int t = threadIdx.x;
  for (int i = t; i < (R * R) / 4; i += 256) ((float4*)Wl)[i] = ((const float4*)Wr)[i];
  __syncthreads();

  int ct = t & 3;              // 4 col-threads x 16 cols = 64 cols
  int rg = t >> 2;             // 64 row-groups x 4 rows = 256 rows/block
  int c0 = ct << 4;
  int row0 = blockIdx.x * 256 + (rg << 2);

  float4 bb[4];
#pragma unroll
  for (int j = 0; j < 4; ++j) bb[j] = *(const float4*)(br + c0 + j * 4);

  float4 acc[4][4];
#pragma unroll
  for (int r = 0; r < 4; ++r)
#pragma unroll
    for (int j = 0; j < 4; ++j) acc[r][j] = bb[j];

  int r0 = row0, r1 = row0 + 1, r2 = row0 + 2, r3 = row0 + 3;
  bool v0 = r0 < e, v1 = r1 < e, v2 = r2 < e, v3 = r3 < e;
  const float4 z4 = make_float4(0.f, 0.f, 0.f, 0.f);
  const float4* A0 = (const float4*)(T + (size_t)(v0 ? r0 : 0) * R);
  const float4* A1 = (const float4*)(T + (size_t)(v1 ? r1 : 0) * R);
  const float4* A2 = (const float4*)(T + (size_t)(v2 ? r2 : 0) * R);
  const float4* A3 = (const float4*)(T + (size_t)(v3 ? r3 : 0) * R);

  if (v0) {  // fully-interior fast path check is per-row below; v0 false => whole group >= e
#pragma unroll 4
    for (int k4 = 0; k4 < 16; ++k4) {
      float4 a0 = A0[k4];
      float4 a1 = v1 ? A1[k4] : z4;
      float4 a2 = v2 ? A2[k4] : z4;
      float4 a3 = v3 ? A3[k4] : z4;
#pragma unroll
      for (int kk = 0; kk < 4; ++kk) {
        float e0 = (kk == 0) ? a0.x : (kk == 1) ? a0.y : (kk == 2) ? a0.z : a0.w;
        float e1 = (kk == 0) ? a1.x : (kk == 1) ? a1.y : (kk == 2) ? a1.z : a1.w;
        float e2 = (kk == 0) ? a2.x : (kk == 1) ? a2.y : (kk == 2) ? a2.z : a2.w;
        float e3 = (kk == 0) ? a3.x : (kk == 1) ? a3.y : (kk == 2) ? a3.z : a3.w;
        const float4* w4 = (const float4*)(Wl + (((k4 << 2) + kk) << 6) + c0);
        float4 w0 = w4[0], w1 = w4[1], w2 = w4[2], w3 = w4[3];
        acc[0][0] = f4fma(e0, w0, acc[0][0]); acc[0][1] = f4fma(e0, w1, acc[0][1]);
        acc[0][2] = f4fma(e0, w2, acc[0][2]); acc[0][3] = f4fma(e0, w3, acc[0][3]);
        acc[1][0] = f4fma(e1, w0, acc[1][0]); acc[1][1] = f4fma(e1, w1, acc[1][1]);
        acc[1][2] = f4fma(e1, w2, acc[1][2]); acc[1][3] = f4fma(e1, w3, acc[1][3]);
        acc[2][0] = f4fma(e2, w0, acc[2][0]); acc[2][1] = f4fma(e2, w1, acc[2][1]);
        acc[2][2] = f4fma(e2, w2, acc[2][2]); acc[2][3] = f4fma(e2, w3, acc[2][3]);
        acc[3][0] = f4fma(e3, w0, acc[3][0]); acc[3][1] = f4fma(e3, w1, acc[3][1]);
        acc[3][2] = f4fma(e3, w2, acc[3][2]); acc[3][3] = f4fma(e3, w3, acc[3][3]);
      }
    }
  }

#pragma unroll
  for (int r = 0; r < 4; ++r) {
    int row = row0 + r;
    if (row < ntot) {
      float4* op = (float4*)(out + (size_t)row * R + c0);
      op[0] = acc[r][0]; op[1] = acc[r][1]; op[2] = acc[r][2]; op[3] = acc[r][3];
    }
  }
}

extern "C" void kernel_launch(void* const* d_in, const int* in_sizes, int n_in,
                              void* d_out, int out_size, void* d_ws, size_t ws_size,
                              hipStream_t stream) {
  const int*   src  = (const int*)d_in[0];
  const int*   dst  = (const int*)d_in[1];
  const float* x    = (const float*)d_in[2];
  const float* text = (const float*)d_in[3];
  const float* W1   = (const float*)d_in[4];
  const float* b1   = (const float*)d_in[5];
  const float* W2   = (const float*)d_in[6];
  const float* b2   = (const float*)d_in[7];
  const float* relW = (const float*)d_in[8];
  const float* relb = (const float*)d_in[9];

  const int E = in_sizes[0];
  const int N = in_sizes[2] / D;

  float* outH = (float*)d_out;
  float* outE = outH + (size_t)N * D;

  // workspace carve-out (256B aligned)
  char* w = (char*)d_ws;
  auto alloc = [&](size_t bytes) -> void* {
    void* p = (void*)w;
    w += (bytes + 255) & ~(size_t)255;
    return p;
  };
  int*   deg_out  = (int*)alloc((size_t)N * 4);
  int*   deg_in   = (int*)alloc((size_t)N * 4);
  int*   cursor   = (int*)alloc((size_t)N * 4);
  float* norm_src = (float*)alloc((size_t)N * 4);
  float* norm_dst = (float*)alloc((size_t)N * 4);
  int*   ovf_cnt  = (int*)alloc(256);
  int2*  ovf      = (int2*)alloc((size_t)OVF_CAP * 8);
  int*   bucket   = (int*)alloc((size_t)N * CAP * 4);
  float* agg      = (float*)alloc((size_t)N * D * 4);

  int nbN = (N + 255) / 256;
  int nbE = (E + 255) / 256;

  k_init<<<nbN, 256, 0, stream>>>(deg_out, deg_in, cursor, ovf_cnt, N);
  k_deg<<<nbE, 256, 0, stream>>>(src, dst, deg_out, deg_in, E);
  k_norm<<<nbN, 256, 0, stream>>>(deg_out, deg_in, norm_src, norm_dst, N);
  k_fill<<<nbE, 256, 0, stream>>>(src, dst, cursor, bucket, ovf_cnt, ovf, E);

  // layer 1: h1 -> outH
  k_agg<<<(N + 7) / 8, 256, 0, stream>>>(x, norm_src, cursor, bucket, agg, N);
  k_ovf<<<64, 128, 0, stream>>>(x, norm_src, ovf_cnt, ovf, agg);
  k_gemm_relu<<<1024, 256, 0, stream>>>(agg, norm_dst, W1, b1, outH, N);

  // layer 2: h2 -> outH (reads outH as input, writes same region after agg)
  k_agg<<<(N + 7) / 8, 256, 0, stream>>>(outH, norm_src, cursor, bucket, agg, N);
  k_ovf<<<64, 128, 0, stream>>>(outH, norm_src, ovf_cnt, ovf, agg);
  k_gemm_relu<<<1024, 256, 0, stream>>>(agg, norm_dst, W2, b2, outH, N);

  // edge features
  int ntot = E + N;
  k_rel<<<(ntot + 255) / 256, 256, 0, stream>>>(text, relW, relb, outE, E, ntot);
}

// Round 4
// 460.777 us; speedup vs baseline: 1.2701x; 1.2701x over previous
//
#include <hip/hip_runtime.h>

// Problem constants (match reference file)
constexpr int D = 128;       // node feature dim
constexpr int R = 64;        // edge feature dim (in = out)
constexpr int CAP = 64;      // per-dst bucket capacity (in-deg ~ Poisson(16))
constexpr int OVF_CAP = 65536;
constexpr int RT = 128;      // k_rel rows per block tile
constexpr int TPAD = 68;     // padded T-tile row stride (floats): +16B kills bank conflicts

static __device__ __forceinline__ float4 f4fma(float a, float4 w, float4 c) {
  c.x = fmaf(a, w.x, c.x); c.y = fmaf(a, w.y, c.y);
  c.z = fmaf(a, w.z, c.z); c.w = fmaf(a, w.w, c.w);
  return c;
}

__global__ void k_init(int* deg_out, int* cursor, int* ovf_cnt, int n) {
  int i = blockIdx.x * blockDim.x + threadIdx.x;
  if (i < n) { deg_out[i] = 1; cursor[i] = 0; }  // deg_out=1: self loop
  if (i == 0) ovf_cnt[0] = 0;
}

// merged degree-count + bucket-fill: deg_in recovered as cursor+1 afterwards
__global__ void k_fill(const int* __restrict__ src, const int* __restrict__ dst,
                       int* deg_out, int* cursor, int* bucket,
                       int* ovf_cnt, int2* ovf, int e) {
  int i = blockIdx.x * blockDim.x + threadIdx.x;
  if (i >= e) return;
  int d = dst[i], s = src[i];
  atomicAdd(&deg_out[s], 1);
  int slot = atomicAdd(&cursor[d], 1);
  if (slot < CAP) bucket[(size_t)d * CAP + slot] = s;
  else {
    int oi = atomicAdd(ovf_cnt, 1);
    if (oi < OVF_CAP) ovf[oi] = make_int2(s, d);
  }
}

__global__ void k_norm(const int* __restrict__ deg_out, const int* __restrict__ cursor,
                       float* ns, float* nd, int n) {
  int i = blockIdx.x * blockDim.x + threadIdx.x;
  if (i < n) {
    ns[i] = rsqrtf((float)deg_out[i]);
    nd[i] = rsqrtf((float)(cursor[i] + 1));   // +1 = self loop
  }
}

// One 32-lane group per node; each lane holds a float4 (D=128 = 32*4).
// agg[v] = x[v]*ns[v] (self loop) + sum_{(s->v)} x[s]*ns[s]   (norm_dst applied later)
__global__ __launch_bounds__(256) void k_agg(const float* __restrict__ X,
                                             const float* __restrict__ ns,
                                             const int* __restrict__ cursor,
                                             const int* __restrict__ bucket,
                                             float* __restrict__ agg, int n) {
  int g = threadIdx.x >> 5, lane = threadIdx.x & 31;
  int v = blockIdx.x * 8 + g;
  if (v >= n) return;
  float4 acc;
  {
    float4 xv = ((const float4*)(X + (size_t)v * D))[lane];
    float s = ns[v];
    acc.x = xv.x * s; acc.y = xv.y * s; acc.z = xv.z * s; acc.w = xv.w * s;
  }
  int cnt = min(cursor[v], CAP);
  const int* bk = bucket + (size_t)v * CAP;
  int i = 0;
  for (; i + 4 <= cnt; i += 4) {
    int s0 = bk[i], s1 = bk[i + 1], s2 = bk[i + 2], s3 = bk[i + 3];
    float n0 = ns[s0], n1 = ns[s1], n2 = ns[s2], n3 = ns[s3];
    float4 x0 = ((const float4*)(X + (size_t)s0 * D))[lane];
    float4 x1 = ((const float4*)(X + (size_t)s1 * D))[lane];
    float4 x2 = ((const float4*)(X + (size_t)s2 * D))[lane];
    float4 x3 = ((const float4*)(X + (size_t)s3 * D))[lane];
    acc = f4fma(n0, x0, acc); acc = f4fma(n1, x1, acc);
    acc = f4fma(n2, x2, acc); acc = f4fma(n3, x3, acc);
  }
  for (; i < cnt; ++i) {
    int s0 = bk[i];
    float4 x0 = ((const float4*)(X + (size_t)s0 * D))[lane];
    acc = f4fma(ns[s0], x0, acc);
  }
  ((float4*)(agg + (size_t)v * D))[lane] = acc;
}

// Rare overflow edges (slot >= CAP): f32 atomics, normally zero work.
__global__ __launch_bounds__(128) void k_ovf(const float* __restrict__ X,
                                             const float* __restrict__ ns,
                                             const int* __restrict__ ovf_cnt,
                                             const int2* __restrict__ ovf,
                                             float* agg) {
  int m = min(ovf_cnt[0], OVF_CAP);
  int t = threadIdx.x;
  for (int i = blockIdx.x; i < m; i += gridDim.x) {
    int2 e = ovf[i];
    atomicAdd(&agg[(size_t)e.y * D + t], X[(size_t)e.x * D + t] * ns[e.x]);
  }
}

// out[r] = relu( (agg[r] * nd[r]) @ W + b ) ; nd folded into epilogue.
__global__ __launch_bounds__(256) void k_gemm_relu(const float* __restrict__ A,
                                                   const float* __restrict__ ndv,
                                                   const float* __restrict__ W,
                                                   const float* __restrict__ bias,
                                                   float* __restrict__ out, int n) {
  __shared__ float Wl[D * D];  // 64 KiB
  int t = threadIdx.x;
  for (int i = t; i < (D * D) / 4; i += 256) ((float4*)Wl)[i] = ((const float4*)W)[i];
  __syncthreads();
  int r2 = (t >> 5) * 2;       // 0,2,...,14
  int cg = (t & 31) * 4;       // col group
  float4 bb = *(const float4*)(bias + cg);
  for (int row0 = blockIdx.x * 16; row0 < n; row0 += gridDim.x * 16) {
    int ra = row0 + r2, rb = ra + 1;
    if (ra >= n) continue;     // no __syncthreads inside loop -> safe
    bool hb = (rb < n);
    const float4* A0 = (const float4*)(A + (size_t)ra * D);
    const float4* A1 = (const float4*)(A + (size_t)(hb ? rb : ra) * D);
    float4 s0 = make_float4(0.f, 0.f, 0.f, 0.f);
    float4 s1 = make_float4(0.f, 0.f, 0.f, 0.f);
#pragma unroll 8
    for (int k4 = 0; k4 < 32; ++k4) {
      float4 a0 = A0[k4];
      float4 a1 = A1[k4];
      const float* wp = Wl + (k4 << 9) + cg;
      float4 w;
      w = *(const float4*)(wp);       s0 = f4fma(a0.x, w, s0); s1 = f4fma(a1.x, w, s1);
      w = *(const float4*)(wp + 128); s0 = f4fma(a0.y, w, s0); s1 = f4fma(a1.y, w, s1);
      w = *(const float4*)(wp + 256); s0 = f4fma(a0.z, w, s0); s1 = f4fma(a1.z, w, s1);
      w = *(const float4*)(wp + 384); s0 = f4fma(a0.w, w, s0); s1 = f4fma(a1.w, w, s1);
    }
    {
      float ndr = ndv[ra];
      float4 o;
      o.x = fmaxf(fmaf(s0.x, ndr, bb.x), 0.f);
      o.y = fmaxf(fmaf(s0.y, ndr, bb.y), 0.f);
      o.z = fmaxf(fmaf(s0.z, ndr, bb.z), 0.f);
      o.w = fmaxf(fmaf(s0.w, ndr, bb.w), 0.f);
      *(float4*)(out + (size_t)ra * D + cg) = o;
    }
    if (hb) {
      float ndr = ndv[rb];
      float4 o;
      o.x = fmaxf(fmaf(s1.x, ndr, bb.x), 0.f);
      o.y = fmaxf(fmaf(s1.y, ndr, bb.y), 0.f);
      o.z = fmaxf(fmaf(s1.z, ndr, bb.z), 0.f);
      o.w = fmaxf(fmaf(s1.w, ndr, bb.w), 0.f);
      *(float4*)(out + (size_t)rb * D + cg) = o;
    }
  }
}

// e_h rows [0,E): text_h[row] @ relW + relb ; rows [E,E+N): relb (zero text).
// v3: LDS-staged T tile (coalesced global loads), 4 rows x 8 cols per thread.
// T tile padded to 68-float rows: bank = (4*rg + 4*k4) % 32, 8 row-groups
// hit 8 disjoint 4-bank sets -> conflict-free. W reads: 2-way (free).
__global__ __launch_bounds__(256) void k_rel(const float* __restrict__ T,
                                             const float* __restrict__ Wr,
                                             const float* __restrict__ br,
                                             float* __restrict__ out,
                                             int e, int ntot) {
  __shared__ float Wl[R * R];     // 16 KiB
  __shared__ float Tl[RT * TPAD]; // 34 KiB
  int t = threadIdx.x;
  for (int i = t; i < (R * R) / 4; i += 256) ((float4*)Wl)[i] = ((const float4*)Wr)[i];

  int row0 = blockIdx.x * RT;
  const float4 z4 = make_float4(0.f, 0.f, 0.f, 0.f);
  // stage 128 rows x 64 floats = 2048 float4s, fully coalesced; zero rows >= e
#pragma unroll
  for (int j = 0; j < 8; ++j) {
    int idx = t + 256 * j;        // float4 index within tile
    int r = idx >> 4;             // local row
    int c4 = idx & 15;            // float4 column
    int grow = row0 + r;
    float4 v = (grow < e) ? ((const float4*)T)[(size_t)grow * 16 + c4] : z4;
    *(float4*)&Tl[r * TPAD + (c4 << 2)] = v;
  }
  __syncthreads();

  int ct = t & 7;                 // 8 col-threads x 8 cols = 64 cols
  int rg = t >> 3;                // 32 row-groups; rows rg + {0,32,64,96}
  int c0 = ct << 3;

  float4 b0 = *(const float4*)(br + c0);
  float4 b1 = *(const float4*)(br + c0 + 4);
  float4 acc[4][2];
#pragma unroll
  for (int r = 0; r < 4; ++r) { acc[r][0] = b0; acc[r][1] = b1; }

#pragma unroll 4
  for (int k4 = 0; k4 < 16; ++k4) {
    float4 a0 = *(const float4*)&Tl[(rg     ) * TPAD + (k4 << 2)];
    float4 a1 = *(const float4*)&Tl[(rg + 32) * TPAD + (k4 << 2)];
    float4 a2 = *(const float4*)&Tl[(rg + 64) * TPAD + (k4 << 2)];
    float4 a3 = *(const float4*)&Tl[(rg + 96) * TPAD + (k4 << 2)];
    const float* wbase = Wl + (k4 << 8) + c0;
#pragma unroll
    for (int kk = 0; kk < 4; ++kk) {
      float4 w0 = *(const float4*)(wbase + (kk << 6));
      float4 w1 = *(const float4*)(wbase + (kk << 6) + 4);
      float e0 = (kk == 0) ? a0.x : (kk == 1) ? a0.y : (kk == 2) ? a0.z : a0.w;
      float e1 = (kk == 0) ? a1.x : (kk == 1) ? a1.y : (kk == 2) ? a1.z : a1.w;
      float e2 = (kk == 0) ? a2.x : (kk == 1) ? a2.y : (kk == 2) ? a2.z : a2.w;
      float e3 = (kk == 0) ? a3.x : (kk == 1) ? a3.y : (kk == 2) ? a3.z : a3.w;
      acc[0][0] = f4fma(e0, w0, acc[0][0]); acc[0][1] = f4fma(e0, w1, acc[0][1]);
      acc[1][0] = f4fma(e1, w0, acc[1][0]); acc[1][1] = f4fma(e1, w1, acc[1][1]);
      acc[2][0] = f4fma(e2, w0, acc[2][0]); acc[2][1] = f4fma(e2, w1, acc[2][1]);
      acc[3][0] = f4fma(e3, w0, acc[3][0]); acc[3][1] = f4fma(e3, w1, acc[3][1]);
    }
  }

#pragma unroll
  for (int r = 0; r < 4; ++r) {
    int row = row0 + rg + 32 * r;
    if (row < ntot) {
      float4* op = (float4*)(out + (size_t)row * R + c0);
      op[0] = acc[r][0]; op[1] = acc[r][1];
    }
  }
}

extern "C" void kernel_launch(void* const* d_in, const int* in_sizes, int n_in,
                              void* d_out, int out_size, void* d_ws, size_t ws_size,
                              hipStream_t stream) {
  const int*   src  = (const int*)d_in[0];
  const int*   dst  = (const int*)d_in[1];
  const float* x    = (const float*)d_in[2];
  const float* text = (const float*)d_in[3];
  const float* W1   = (const float*)d_in[4];
  const float* b1   = (const float*)d_in[5];
  const float* W2   = (const float*)d_in[6];
  const float* b2   = (const float*)d_in[7];
  const float* relW = (const float*)d_in[8];
  const float* relb = (const float*)d_in[9];

  const int E = in_sizes[0];
  const int N = in_sizes[2] / D;

  float* outH = (float*)d_out;
  float* outE = outH + (size_t)N * D;

  // workspace carve-out (256B aligned)
  char* w = (char*)d_ws;
  auto alloc = [&](size_t bytes) -> void* {
    void* p = (void*)w;
    w += (bytes + 255) & ~(size_t)255;
    return p;
  };
  int*   deg_out  = (int*)alloc((size_t)N * 4);
  int*   cursor   = (int*)alloc((size_t)N * 4);
  float* norm_src = (float*)alloc((size_t)N * 4);
  float* norm_dst = (float*)alloc((size_t)N * 4);
  int*   ovf_cnt  = (int*)alloc(256);
  int2*  ovf      = (int2*)alloc((size_t)OVF_CAP * 8);
  int*   bucket   = (int*)alloc((size_t)N * CAP * 4);
  float* agg      = (float*)alloc((size_t)N * D * 4);

  int nbN = (N + 255) / 256;
  int nbE = (E + 255) / 256;

  k_init<<<nbN, 256, 0, stream>>>(deg_out, cursor, ovf_cnt, N);
  k_fill<<<nbE, 256, 0, stream>>>(src, dst, deg_out, cursor, bucket, ovf_cnt, ovf, E);
  k_norm<<<nbN, 256, 0, stream>>>(deg_out, cursor, norm_src, norm_dst, N);

  // layer 1: h1 -> outH
  k_agg<<<(N + 7) / 8, 256, 0, stream>>>(x, norm_src, cursor, bucket, agg, N);
  k_ovf<<<64, 128, 0, stream>>>(x, norm_src, ovf_cnt, ovf, agg);
  k_gemm_relu<<<1024, 256, 0, stream>>>(agg, norm_dst, W1, b1, outH, N);

  // layer 2: h2 -> outH (reads outH as input, writes same region after agg)
  k_agg<<<(N + 7) / 8, 256, 0, stream>>>(outH, norm_src, cursor, bucket, agg, N);
  k_ovf<<<64, 128, 0, stream>>>(outH, norm_src, ovf_cnt, ovf, agg);
  k_gemm_relu<<<1024, 256, 0, stream>>>(agg, norm_dst, W2, b2, outH, N);

  // edge features
  int ntot = E + N;
  k_rel<<<(ntot + RT - 1) / RT, 256, 0, stream>>>(text, relW, relb, outE, E, ntot);
}

// Round 6
// 447.135 us; speedup vs baseline: 1.3089x; 1.0305x over previous
//
#include <hip/hip_runtime.h>

// Problem constants (match reference file)
constexpr int D = 128;       // node feature dim
constexpr int R = 64;        // edge feature dim (in = out)
constexpr int CAP = 64;      // per-dst bucket capacity (in-deg ~ Poisson(16))
constexpr int OVF_CAP = 65536;
constexpr int TPAD = 68;     // padded T-tile row stride (floats): banks 4*rg+4*k4, conflict-free

static __device__ __forceinline__ float4 f4fma(float a, float4 w, float4 c) {
  c.x = fmaf(a, w.x, c.x); c.y = fmaf(a, w.y, c.y);
  c.z = fmaf(a, w.z, c.z); c.w = fmaf(a, w.w, c.w);
  return c;
}

__global__ void k_init(int* deg_out, int* cursor, int* ovf_cnt, int n) {
  int i = blockIdx.x * blockDim.x + threadIdx.x;
  if (i < n) { deg_out[i] = 1; cursor[i] = 0; }  // deg_out=1: self loop
  if (i == 0) ovf_cnt[0] = 0;
}

// merged degree-count + bucket-fill: deg_in recovered as cursor+1 afterwards
__global__ void k_fill(const int* __restrict__ src, const int* __restrict__ dst,
                       int* deg_out, int* cursor, int* bucket,
                       int* ovf_cnt, int2* ovf, int e) {
  int i = blockIdx.x * blockDim.x + threadIdx.x;
  if (i >= e) return;
  int d = dst[i], s = src[i];
  atomicAdd(&deg_out[s], 1);
  int slot = atomicAdd(&cursor[d], 1);
  if (slot < CAP) bucket[(size_t)d * CAP + slot] = s;
  else {
    int oi = atomicAdd(ovf_cnt, 1);
    if (oi < OVF_CAP) ovf[oi] = make_int2(s, d);
  }
}

__global__ void k_norm(const int* __restrict__ deg_out, const int* __restrict__ cursor,
                       float* ns, float* nd, int n) {
  int i = blockIdx.x * blockDim.x + threadIdx.x;
  if (i < n) {
    ns[i] = rsqrtf((float)deg_out[i]);
    nd[i] = rsqrtf((float)(cursor[i] + 1));   // +1 = self loop
  }
}

// One 32-lane group per node; each lane holds a float4 (D=128 = 32*4).
// agg[v] = x[v]*ns[v] (self loop) + sum_{(s->v)} x[s]*ns[s]   (norm_dst applied later)
__global__ __launch_bounds__(256) void k_agg(const float* __restrict__ X,
                                             const float* __restrict__ ns,
                                             const int* __restrict__ cursor,
                                             const int* __restrict__ bucket,
                                             float* __restrict__ agg, int n) {
  int g = threadIdx.x >> 5, lane = threadIdx.x & 31;
  int v = blockIdx.x * 8 + g;
  if (v >= n) return;
  float4 acc;
  {
    float4 xv = ((const float4*)(X + (size_t)v * D))[lane];
    float s = ns[v];
    acc.x = xv.x * s; acc.y = xv.y * s; acc.z = xv.z * s; acc.w = xv.w * s;
  }
  int cnt = min(cursor[v], CAP);
  const int* bk = bucket + (size_t)v * CAP;
  int i = 0;
  for (; i + 4 <= cnt; i += 4) {
    int s0 = bk[i], s1 = bk[i + 1], s2 = bk[i + 2], s3 = bk[i + 3];
    float n0 = ns[s0], n1 = ns[s1], n2 = ns[s2], n3 = ns[s3];
    float4 x0 = ((const float4*)(X + (size_t)s0 * D))[lane];
    float4 x1 = ((const float4*)(X + (size_t)s1 * D))[lane];
    float4 x2 = ((const float4*)(X + (size_t)s2 * D))[lane];
    float4 x3 = ((const float4*)(X + (size_t)s3 * D))[lane];
    acc = f4fma(n0, x0, acc); acc = f4fma(n1, x1, acc);
    acc = f4fma(n2, x2, acc); acc = f4fma(n3, x3, acc);
  }
  for (; i < cnt; ++i) {
    int s0 = bk[i];
    float4 x0 = ((const float4*)(X + (size_t)s0 * D))[lane];
    acc = f4fma(ns[s0], x0, acc);
  }
  ((float4*)(agg + (size_t)v * D))[lane] = acc;
}

// Rare overflow edges (slot >= CAP): f32 atomics, normally zero work.
__global__ __launch_bounds__(128) void k_ovf(const float* __restrict__ X,
                                             const float* __restrict__ ns,
                                             const int* __restrict__ ovf_cnt,
                                             const int2* __restrict__ ovf,
                                             float* agg) {
  int m = min(ovf_cnt[0], OVF_CAP);
  int t = threadIdx.x;
  for (int i = blockIdx.x; i < m; i += gridDim.x) {
    int2 e = ovf[i];
    atomicAdd(&agg[(size_t)e.y * D + t], X[(size_t)e.x * D + t] * ns[e.x]);
  }
}

// out[r] = relu( (agg[r] @ W)*nd[r] + b ). 64-row tile per block.
// Thread: 4 rows (rg+{0,16,32,48}) x 8 cols (c0..c0+3, c0+64..c0+67).
// Col split keeps W LDS b128 reads 2-way (free); FMA:LDS = 8192:3072 cyc -> VALU-bound.
__global__ __launch_bounds__(256) void k_gemm_relu(const float* __restrict__ A,
                                                   const float* __restrict__ ndv,
                                                   const float* __restrict__ W,
                                                   const float* __restrict__ bias,
                                                   float* __restrict__ out, int n) {
  __shared__ float Wl[D * D];  // 64 KiB
  int t = threadIdx.x;
  for (int i = t; i < (D * D) / 4; i += 256) ((float4*)Wl)[i] = ((const float4*)W)[i];
  __syncthreads();

  int ct = t & 15, rg = t >> 4;
  int c0 = ct << 2;            // cols c0..c0+3 and c0+64..c0+67
  int row0 = blockIdx.x * 64;

  float4 bb0 = *(const float4*)(bias + c0);
  float4 bb1 = *(const float4*)(bias + c0 + 64);

  int r[4]; const float4* Ap[4];
#pragma unroll
  for (int m = 0; m < 4; ++m) {
    r[m] = row0 + rg + 16 * m;
    int rc = (r[m] < n) ? r[m] : (n - 1);
    Ap[m] = (const float4*)(A + (size_t)rc * D);
  }

  float4 acc[4][2];
#pragma unroll
  for (int m = 0; m < 4; ++m) {
    acc[m][0] = make_float4(0.f, 0.f, 0.f, 0.f);
    acc[m][1] = make_float4(0.f, 0.f, 0.f, 0.f);
  }

#pragma unroll 8
  for (int k4 = 0; k4 < 32; ++k4) {
    float4 a0 = Ap[0][k4], a1 = Ap[1][k4], a2 = Ap[2][k4], a3 = Ap[3][k4];
    const float* wbase = Wl + (k4 << 9) + c0;
#pragma unroll
    for (int kk = 0; kk < 4; ++kk) {
      float4 w0 = *(const float4*)(wbase + (kk << 7));
      float4 w1 = *(const float4*)(wbase + (kk << 7) + 64);
      float e0 = (kk == 0) ? a0.x : (kk == 1) ? a0.y : (kk == 2) ? a0.z : a0.w;
      float e1 = (kk == 0) ? a1.x : (kk == 1) ? a1.y : (kk == 2) ? a1.z : a1.w;
      float e2 = (kk == 0) ? a2.x : (kk == 1) ? a2.y : (kk == 2) ? a2.z : a2.w;
      float e3 = (kk == 0) ? a3.x : (kk == 1) ? a3.y : (kk == 2) ? a3.z : a3.w;
      acc[0][0] = f4fma(e0, w0, acc[0][0]); acc[0][1] = f4fma(e0, w1, acc[0][1]);
      acc[1][0] = f4fma(e1, w0, acc[1][0]); acc[1][1] = f4fma(e1, w1, acc[1][1]);
      acc[2][0] = f4fma(e2, w0, acc[2][0]); acc[2][1] = f4fma(e2, w1, acc[2][1]);
      acc[3][0] = f4fma(e3, w0, acc[3][0]); acc[3][1] = f4fma(e3, w1, acc[3][1]);
    }
  }

#pragma unroll
  for (int m = 0; m < 4; ++m) {
    if (r[m] < n) {
      float ndr = ndv[r[m]];
      float4 o0, o1;
      o0.x = fmaxf(fmaf(acc[m][0].x, ndr, bb0.x), 0.f);
      o0.y = fmaxf(fmaf(acc[m][0].y, ndr, bb0.y), 0.f);
      o0.z = fmaxf(fmaf(acc[m][0].z, ndr, bb0.z), 0.f);
      o0.w = fmaxf(fmaf(acc[m][0].w, ndr, bb0.w), 0.f);
      o1.x = fmaxf(fmaf(acc[m][1].x, ndr, bb1.x), 0.f);
      o1.y = fmaxf(fmaf(acc[m][1].y, ndr, bb1.y), 0.f);
      o1.z = fmaxf(fmaf(acc[m][1].z, ndr, bb1.z), 0.f);
      o1.w = fmaxf(fmaf(acc[m][1].w, ndr, bb1.w), 0.f);
      *(float4*)(out + (size_t)r[m] * D + c0) = o0;
      *(float4*)(out + (size_t)r[m] * D + c0 + 64) = o1;
    }
  }
}

// e_h rows [0,E): text_h[row] @ relW + relb ; rows [E,E+N): relb (zero text).
// v4: software-pipelined grid-stride tiles of 64 rows. Prefetch next tile into
// 4 float4 regs before compute; regs->LDS after barrier (T14 issue-early/write-late).
// LDS = 16KB W + 17KB T = 33.8KB -> 4 blocks/CU. 4 rows x 4 cols per thread.
__global__ __launch_bounds__(256) void k_rel(const float* __restrict__ T,
                                             const float* __restrict__ Wr,
                                             const float* __restrict__ br,
                                             float* __restrict__ out,
                                             int e, int ntot, int nTiles) {
  __shared__ float Wl[R * R];      // 16 KiB
  __shared__ float Tl[64 * TPAD];  // 17 KiB
  int t = threadIdx.x;
  for (int i = t; i < (R * R) / 4; i += 256) ((float4*)Wl)[i] = ((const float4*)Wr)[i];

  int ct = t & 15, rg = t >> 4;
  int c0 = ct << 2;
  float4 bb = *(const float4*)(br + c0);
  const float4 z4 = make_float4(0.f, 0.f, 0.f, 0.f);

  int tile = blockIdx.x;
  float4 pre[4];
  if (tile < nTiles) {
#pragma unroll
    for (int j = 0; j < 4; ++j) {
      int q = t + 256 * j, rr = q >> 4, c4 = q & 15;
      int grow = tile * 64 + rr;
      pre[j] = (grow < e) ? ((const float4*)T)[(size_t)grow * 16 + c4] : z4;
    }
  }

  for (; tile < nTiles; tile += gridDim.x) {
    __syncthreads();                 // previous compute done reading Tl
#pragma unroll
    for (int j = 0; j < 4; ++j) {    // regs -> LDS (waits vmcnt of prefetch)
      int q = t + 256 * j, rr = q >> 4, c4 = q & 15;
      *(float4*)&Tl[rr * TPAD + (c4 << 2)] = pre[j];
    }
    __syncthreads();

    int ntile = tile + gridDim.x;    // issue next prefetch early - hides under compute
    if (ntile < nTiles) {
#pragma unroll
      for (int j = 0; j < 4; ++j) {
        int q = t + 256 * j, rr = q >> 4, c4 = q & 15;
        int grow = ntile * 64 + rr;
        pre[j] = (grow < e) ? ((const float4*)T)[(size_t)grow * 16 + c4] : z4;
      }
    }

    float4 acc0 = bb, acc1 = bb, acc2 = bb, acc3 = bb;
#pragma unroll 4
    for (int k4 = 0; k4 < 16; ++k4) {
      float4 a0 = *(const float4*)&Tl[(rg     ) * TPAD + (k4 << 2)];
      float4 a1 = *(const float4*)&Tl[(rg + 16) * TPAD + (k4 << 2)];
      float4 a2 = *(const float4*)&Tl[(rg + 32) * TPAD + (k4 << 2)];
      float4 a3 = *(const float4*)&Tl[(rg + 48) * TPAD + (k4 << 2)];
      const float* wbase = Wl + (k4 << 8) + c0;
#pragma unroll
      for (int kk = 0; kk < 4; ++kk) {
        float4 w = *(const float4*)(wbase + (kk << 6));
        float e0 = (kk == 0) ? a0.x : (kk == 1) ? a0.y : (kk == 2) ? a0.z : a0.w;
        float e1 = (kk == 0) ? a1.x : (kk == 1) ? a1.y : (kk == 2) ? a1.z : a1.w;
        float e2 = (kk == 0) ? a2.x : (kk == 1) ? a2.y : (kk == 2) ? a2.z : a2.w;
        float e3 = (kk == 0) ? a3.x : (kk == 1) ? a3.y : (kk == 2) ? a3.z : a3.w;
        acc0 = f4fma(e0, w, acc0);
        acc1 = f4fma(e1, w, acc1);
        acc2 = f4fma(e2, w, acc2);
        acc3 = f4fma(e3, w, acc3);
      }
    }

    int base = tile * 64;
    if (base + rg      < ntot) *(float4*)(out + (size_t)(base + rg     ) * R + c0) = acc0;
    if (base + rg + 16 < ntot) *(float4*)(out + (size_t)(base + rg + 16) * R + c0) = acc1;
    if (base + rg + 32 < ntot) *(float4*)(out + (size_t)(base + rg + 32) * R + c0) = acc2;
    if (base + rg + 48 < ntot) *(float4*)(out + (size_t)(base + rg + 48) * R + c0) = acc3;
  }
}

extern "C" void kernel_launch(void* const* d_in, const int* in_sizes, int n_in,
                              void* d_out, int out_size, void* d_ws, size_t ws_size,
                              hipStream_t stream) {
  const int*   src  = (const int*)d_in[0];
  const int*   dst  = (const int*)d_in[1];
  const float* x    = (const float*)d_in[2];
  const float* text = (const float*)d_in[3];
  const float* W1   = (const float*)d_in[4];
  const float* b1   = (const float*)d_in[5];
  const float* W2   = (const float*)d_in[6];
  const float* b2   = (const float*)d_in[7];
  const float* relW = (const float*)d_in[8];
  const float* relb = (const float*)d_in[9];

  const int E = in_sizes[0];
  const int N = in_sizes[2] / D;

  float* outH = (float*)d_out;
  float* outE = outH + (size_t)N * D;

  // workspace carve-out (256B aligned)
  char* w = (char*)d_ws;
  auto alloc = [&](size_t bytes) -> void* {
    void* p = (void*)w;
    w += (bytes + 255) & ~(size_t)255;
    return p;
  };
  int*   deg_out  = (int*)alloc((size_t)N * 4);
  int*   cursor   = (int*)alloc((size_t)N * 4);
  float* norm_src = (float*)alloc((size_t)N * 4);
  float* norm_dst = (float*)alloc((size_t)N * 4);
  int*   ovf_cnt  = (int*)alloc(256);
  int2*  ovf      = (int2*)alloc((size_t)OVF_CAP * 8);
  int*   bucket   = (int*)alloc((size_t)N * CAP * 4);
  float* agg      = (float*)alloc((size_t)N * D * 4);

  int nbN = (N + 255) / 256;
  int nbE = (E + 255) / 256;

  k_init<<<nbN, 256, 0, stream>>>(deg_out, cursor, ovf_cnt, N);
  k_fill<<<nbE, 256, 0, stream>>>(src, dst, deg_out, cursor, bucket, ovf_cnt, ovf, E);
  k_norm<<<nbN, 256, 0, stream>>>(deg_out, cursor, norm_src, norm_dst, N);

  // layer 1: h1 -> outH
  k_agg<<<(N + 7) / 8, 256, 0, stream>>>(x, norm_src, cursor, bucket, agg, N);
  k_ovf<<<64, 128, 0, stream>>>(x, norm_src, ovf_cnt, ovf, agg);
  k_gemm_relu<<<(N + 63) / 64, 256, 0, stream>>>(agg, norm_dst, W1, b1, outH, N);

  // layer 2: h2 -> outH (reads outH as input, writes same region after agg)
  k_agg<<<(N + 7) / 8, 256, 0, stream>>>(outH, norm_src, cursor, bucket, agg, N);
  k_ovf<<<64, 128, 0, stream>>>(outH, norm_src, ovf_cnt, ovf, agg);
  k_gemm_relu<<<(N + 63) / 64, 256, 0, stream>>>(agg, norm_dst, W2, b2, outH, N);

  // edge features
  int ntot = E + N;
  int nTiles = (ntot + 63) / 64;
  k_rel<<<1536, 256, 0, stream>>>(text, relW, relb, outE, E, ntot, nTiles);
}

// Round 8
// 412.615 us; speedup vs baseline: 1.4184x; 1.0837x over previous
//
#include <hip/hip_runtime.h>

// Problem constants (match reference file)
constexpr int D = 128;       // node feature dim
constexpr int R = 64;        // edge feature dim (in = out)
constexpr int CAP = 64;      // per-dst bucket capacity (in-deg ~ Poisson(16))
constexpr int OVF_CAP = 65536;
constexpr int TPAD = 68;     // padded T-tile row stride (floats): banks 4*rg+4*k4, conflict-free

typedef float floatx4 __attribute__((ext_vector_type(4)));  // native vec for nontemporal builtins

static __device__ __forceinline__ float4 f4fma(float a, float4 w, float4 c) {
  c.x = fmaf(a, w.x, c.x); c.y = fmaf(a, w.y, c.y);
  c.z = fmaf(a, w.z, c.z); c.w = fmaf(a, w.w, c.w);
  return c;
}

static __device__ __forceinline__ void nt_store4(float4 v, float* p) {
  floatx4 q; q.x = v.x; q.y = v.y; q.z = v.z; q.w = v.w;
  __builtin_nontemporal_store(q, (floatx4*)p);
}

__global__ void k_init(int* deg_out, int* cursor, int* ovf_cnt, int n) {
  int i = blockIdx.x * blockDim.x + threadIdx.x;
  if (i < n) { deg_out[i] = 1; cursor[i] = 0; }  // deg_out=1: self loop
  if (i == 0) ovf_cnt[0] = 0;
}

// merged degree-count + bucket-fill: deg_in recovered as cursor+1 afterwards
__global__ void k_fill(const int* __restrict__ src, const int* __restrict__ dst,
                       int* deg_out, int* cursor, int* bucket,
                       int* ovf_cnt, int2* ovf, int e) {
  int i = blockIdx.x * blockDim.x + threadIdx.x;
  if (i >= e) return;
  int d = dst[i], s = src[i];
  atomicAdd(&deg_out[s], 1);
  int slot = atomicAdd(&cursor[d], 1);
  if (slot < CAP) bucket[(size_t)d * CAP + slot] = s;
  else {
    int oi = atomicAdd(ovf_cnt, 1);
    if (oi < OVF_CAP) ovf[oi] = make_int2(s, d);
  }
}

__global__ void k_norm(const int* __restrict__ deg_out, const int* __restrict__ cursor,
                       float* ns, float* nd, int n) {
  int i = blockIdx.x * blockDim.x + threadIdx.x;
  if (i < n) {
    ns[i] = rsqrtf((float)deg_out[i]);
    nd[i] = rsqrtf((float)(cursor[i] + 1));   // +1 = self loop
  }
}

// One 32-lane group per node; each lane holds a float4 (D=128 = 32*4).
// agg[v] = x[v]*ns[v] (self loop) + sum_{(s->v)} x[s]*ns[s]   (norm_dst applied later)
__global__ __launch_bounds__(256) void k_agg(const float* __restrict__ X,
                                             const float* __restrict__ ns,
                                             const int* __restrict__ cursor,
                                             const int* __restrict__ bucket,
                                             float* __restrict__ agg, int n) {
  int g = threadIdx.x >> 5, lane = threadIdx.x & 31;
  int v = blockIdx.x * 8 + g;
  if (v >= n) return;
  float4 acc;
  {
    float4 xv = ((const float4*)(X + (size_t)v * D))[lane];
    float s = ns[v];
    acc.x = xv.x * s; acc.y = xv.y * s; acc.z = xv.z * s; acc.w = xv.w * s;
  }
  int cnt = min(cursor[v], CAP);
  const int* bk = bucket + (size_t)v * CAP;
  int i = 0;
  for (; i + 4 <= cnt; i += 4) {
    int s0 = bk[i], s1 = bk[i + 1], s2 = bk[i + 2], s3 = bk[i + 3];
    float n0 = ns[s0], n1 = ns[s1], n2 = ns[s2], n3 = ns[s3];
    float4 x0 = ((const float4*)(X + (size_t)s0 * D))[lane];
    float4 x1 = ((const float4*)(X + (size_t)s1 * D))[lane];
    float4 x2 = ((const float4*)(X + (size_t)s2 * D))[lane];
    float4 x3 = ((const float4*)(X + (size_t)s3 * D))[lane];
    acc = f4fma(n0, x0, acc); acc = f4fma(n1, x1, acc);
    acc = f4fma(n2, x2, acc); acc = f4fma(n3, x3, acc);
  }
  for (; i < cnt; ++i) {
    int s0 = bk[i];
    float4 x0 = ((const float4*)(X + (size_t)s0 * D))[lane];
    acc = f4fma(ns[s0], x0, acc);
  }
  ((float4*)(agg + (size_t)v * D))[lane] = acc;
}

// Rare overflow edges (slot >= CAP): f32 atomics, normally zero work.
__global__ __launch_bounds__(128) void k_ovf(const float* __restrict__ X,
                                             const float* __restrict__ ns,
                                             const int* __restrict__ ovf_cnt,
                                             const int2* __restrict__ ovf,
                                             float* agg) {
  int m = min(ovf_cnt[0], OVF_CAP);
  int t = threadIdx.x;
  for (int i = blockIdx.x; i < m; i += gridDim.x) {
    int2 e = ovf[i];
    atomicAdd(&agg[(size_t)e.y * D + t], X[(size_t)e.x * D + t] * ns[e.x]);
  }
}

// out[r] = relu( (agg[r] @ W)*nd[r] + b ). 64-row tile per block.
// Thread: 4 rows (rg+{0,16,32,48}) x 8 cols (c0..c0+3, c0+64..c0+67).
// Col split keeps W LDS b128 reads 2-way (free); FMA:LDS = 8192:3072 cyc -> VALU-bound.
__global__ __launch_bounds__(256) void k_gemm_relu(const float* __restrict__ A,
                                                   const float* __restrict__ ndv,
                                                   const float* __restrict__ W,
                                                   const float* __restrict__ bias,
                                                   float* __restrict__ out, int n) {
  __shared__ float Wl[D * D];  // 64 KiB
  int t = threadIdx.x;
  for (int i = t; i < (D * D) / 4; i += 256) ((float4*)Wl)[i] = ((const float4*)W)[i];
  __syncthreads();

  int ct = t & 15, rg = t >> 4;
  int c0 = ct << 2;            // cols c0..c0+3 and c0+64..c0+67
  int row0 = blockIdx.x * 64;

  float4 bb0 = *(const float4*)(bias + c0);
  float4 bb1 = *(const float4*)(bias + c0 + 64);

  int r[4]; const float4* Ap[4];
#pragma unroll
  for (int m = 0; m < 4; ++m) {
    r[m] = row0 + rg + 16 * m;
    int rc = (r[m] < n) ? r[m] : (n - 1);
    Ap[m] = (const float4*)(A + (size_t)rc * D);
  }

  float4 acc[4][2];
#pragma unroll
  for (int m = 0; m < 4; ++m) {
    acc[m][0] = make_float4(0.f, 0.f, 0.f, 0.f);
    acc[m][1] = make_float4(0.f, 0.f, 0.f, 0.f);
  }

#pragma unroll 8
  for (int k4 = 0; k4 < 32; ++k4) {
    float4 a0 = Ap[0][k4], a1 = Ap[1][k4], a2 = Ap[2][k4], a3 = Ap[3][k4];
    const float* wbase = Wl + (k4 << 9) + c0;
#pragma unroll
    for (int kk = 0; kk < 4; ++kk) {
      float4 w0 = *(const float4*)(wbase + (kk << 7));
      float4 w1 = *(const float4*)(wbase + (kk << 7) + 64);
      float e0 = (kk == 0) ? a0.x : (kk == 1) ? a0.y : (kk == 2) ? a0.z : a0.w;
      float e1 = (kk == 0) ? a1.x : (kk == 1) ? a1.y : (kk == 2) ? a1.z : a1.w;
      float e2 = (kk == 0) ? a2.x : (kk == 1) ? a2.y : (kk == 2) ? a2.z : a2.w;
      float e3 = (kk == 0) ? a3.x : (kk == 1) ? a3.y : (kk == 2) ? a3.z : a3.w;
      acc[0][0] = f4fma(e0, w0, acc[0][0]); acc[0][1] = f4fma(e0, w1, acc[0][1]);
      acc[1][0] = f4fma(e1, w0, acc[1][0]); acc[1][1] = f4fma(e1, w1, acc[1][1]);
      acc[2][0] = f4fma(e2, w0, acc[2][0]); acc[2][1] = f4fma(e2, w1, acc[2][1]);
      acc[3][0] = f4fma(e3, w0, acc[3][0]); acc[3][1] = f4fma(e3, w1, acc[3][1]);
    }
  }

#pragma unroll
  for (int m = 0; m < 4; ++m) {
    if (r[m] < n) {
      float ndr = ndv[r[m]];
      float4 o0, o1;
      o0.x = fmaxf(fmaf(acc[m][0].x, ndr, bb0.x), 0.f);
      o0.y = fmaxf(fmaf(acc[m][0].y, ndr, bb0.y), 0.f);
      o0.z = fmaxf(fmaf(acc[m][0].z, ndr, bb0.z), 0.f);
      o0.w = fmaxf(fmaf(acc[m][0].w, ndr, bb0.w), 0.f);
      o1.x = fmaxf(fmaf(acc[m][1].x, ndr, bb1.x), 0.f);
      o1.y = fmaxf(fmaf(acc[m][1].y, ndr, bb1.y), 0.f);
      o1.z = fmaxf(fmaf(acc[m][1].z, ndr, bb1.z), 0.f);
      o1.w = fmaxf(fmaf(acc[m][1].w, ndr, bb1.w), 0.f);
      *(float4*)(out + (size_t)r[m] * D + c0) = o0;
      *(float4*)(out + (size_t)r[m] * D + c0 + 64) = o1;
    }
  }
}

// e_h rows [0,E): text_h[row] @ relW + relb ; rows [E,E+N): relb (zero text).
// v5: ONE 64-row tile per block, blocks in dispatch order (streaming writes —
// R4 empirically showed ~1.1x write traffic vs grid-stride's 2.0x).
// T global loads issued FIRST (hide under W staging). Non-temporal out stores
// (e_h never re-read) keep L2 clean. LDS 33.8KB -> 4 blocks/CU.
__global__ __launch_bounds__(256) void k_rel(const float* __restrict__ T,
                                             const float* __restrict__ Wr,
                                             const float* __restrict__ br,
                                             float* __restrict__ out,
                                             int e, int ntot) {
  __shared__ float Wl[R * R];      // 16 KiB
  __shared__ float Tl[64 * TPAD];  // 17 KiB
  int t = threadIdx.x;
  int tile = blockIdx.x;
  const float4 z4 = make_float4(0.f, 0.f, 0.f, 0.f);

  // issue T-tile loads first: 4 coalesced float4 loads per thread
  float4 pre[4];
#pragma unroll
  for (int j = 0; j < 4; ++j) {
    int q = t + 256 * j, rr = q >> 4, c4 = q & 15;
    int grow = tile * 64 + rr;
    pre[j] = (grow < e) ? ((const float4*)T)[(size_t)grow * 16 + c4] : z4;
  }
  // W staging overlaps the T loads in flight
  for (int i = t; i < (R * R) / 4; i += 256) ((float4*)Wl)[i] = ((const float4*)Wr)[i];
#pragma unroll
  for (int j = 0; j < 4; ++j) {
    int q = t + 256 * j, rr = q >> 4, c4 = q & 15;
    *(float4*)&Tl[rr * TPAD + (c4 << 2)] = pre[j];
  }
  __syncthreads();

  int ct = t & 15, rg = t >> 4;
  int c0 = ct << 2;
  float4 bb = *(const float4*)(br + c0);

  float4 acc0 = bb, acc1 = bb, acc2 = bb, acc3 = bb;
#pragma unroll 4
  for (int k4 = 0; k4 < 16; ++k4) {
    float4 a0 = *(const float4*)&Tl[(rg     ) * TPAD + (k4 << 2)];
    float4 a1 = *(const float4*)&Tl[(rg + 16) * TPAD + (k4 << 2)];
    float4 a2 = *(const float4*)&Tl[(rg + 32) * TPAD + (k4 << 2)];
    float4 a3 = *(const float4*)&Tl[(rg + 48) * TPAD + (k4 << 2)];
    const float* wbase = Wl + (k4 << 8) + c0;
#pragma unroll
    for (int kk = 0; kk < 4; ++kk) {
      float4 w = *(const float4*)(wbase + (kk << 6));
      float e0 = (kk == 0) ? a0.x : (kk == 1) ? a0.y : (kk == 2) ? a0.z : a0.w;
      float e1 = (kk == 0) ? a1.x : (kk == 1) ? a1.y : (kk == 2) ? a1.z : a1.w;
      float e2 = (kk == 0) ? a2.x : (kk == 1) ? a2.y : (kk == 2) ? a2.z : a2.w;
      float e3 = (kk == 0) ? a3.x : (kk == 1) ? a3.y : (kk == 2) ? a3.z : a3.w;
      acc0 = f4fma(e0, w, acc0);
      acc1 = f4fma(e1, w, acc1);
      acc2 = f4fma(e2, w, acc2);
      acc3 = f4fma(e3, w, acc3);
    }
  }

  int base = tile * 64;
  if (base + rg      < ntot) nt_store4(acc0, out + (size_t)(base + rg     ) * R + c0);
  if (base + rg + 16 < ntot) nt_store4(acc1, out + (size_t)(base + rg + 16) * R + c0);
  if (base + rg + 32 < ntot) nt_store4(acc2, out + (size_t)(base + rg + 32) * R + c0);
  if (base + rg + 48 < ntot) nt_store4(acc3, out + (size_t)(base + rg + 48) * R + c0);
}

extern "C" void kernel_launch(void* const* d_in, const int* in_sizes, int n_in,
                              void* d_out, int out_size, void* d_ws, size_t ws_size,
                              hipStream_t stream) {
  const int*   src  = (const int*)d_in[0];
  const int*   dst  = (const int*)d_in[1];
  const float* x    = (const float*)d_in[2];
  const float* text = (const float*)d_in[3];
  const float* W1   = (const float*)d_in[4];
  const float* b1   = (const float*)d_in[5];
  const float* W2   = (const float*)d_in[6];
  const float* b2   = (const float*)d_in[7];
  const float* relW = (const float*)d_in[8];
  const float* relb = (const float*)d_in[9];

  const int E = in_sizes[0];
  const int N = in_sizes[2] / D;

  float* outH = (float*)d_out;
  float* outE = outH + (size_t)N * D;

  // workspace carve-out (256B aligned)
  char* w = (char*)d_ws;
  auto alloc = [&](size_t bytes) -> void* {
    void* p = (void*)w;
    w += (bytes + 255) & ~(size_t)255;
    return p;
  };
  int*   deg_out  = (int*)alloc((size_t)N * 4);
  int*   cursor   = (int*)alloc((size_t)N * 4);
  float* norm_src = (float*)alloc((size_t)N * 4);
  float* norm_dst = (float*)alloc((size_t)N * 4);
  int*   ovf_cnt  = (int*)alloc(256);
  int2*  ovf      = (int2*)alloc((size_t)OVF_CAP * 8);
  int*   bucket   = (int*)alloc((size_t)N * CAP * 4);
  float* agg      = (float*)alloc((size_t)N * D * 4);

  int nbN = (N + 255) / 256;
  int nbE = (E + 255) / 256;

  k_init<<<nbN, 256, 0, stream>>>(deg_out, cursor, ovf_cnt, N);
  k_fill<<<nbE, 256, 0, stream>>>(src, dst, deg_out, cursor, bucket, ovf_cnt, ovf, E);
  k_norm<<<nbN, 256, 0, stream>>>(deg_out, cursor, norm_src, norm_dst, N);

  // layer 1: h1 -> outH
  k_agg<<<(N + 7) / 8, 256, 0, stream>>>(x, norm_src, cursor, bucket, agg, N);
  k_ovf<<<64, 128, 0, stream>>>(x, norm_src, ovf_cnt, ovf, agg);
  k_gemm_relu<<<(N + 63) / 64, 256, 0, stream>>>(agg, norm_dst, W1, b1, outH, N);

  // layer 2: h2 -> outH (reads outH as input, writes same region after agg)
  k_agg<<<(N + 7) / 8, 256, 0, stream>>>(outH, norm_src, cursor, bucket, agg, N);
  k_ovf<<<64, 128, 0, stream>>>(outH, norm_src, ovf_cnt, ovf, agg);
  k_gemm_relu<<<(N + 63) / 64, 256, 0, stream>>>(agg, norm_dst, W2, b2, outH, N);

  // edge features
  int ntot = E + N;
  int nTiles = (ntot + 63) / 64;
  k_rel<<<nTiles, 256, 0, stream>>>(text, relW, relb, outE, E, ntot);
}